// Round 6
// baseline (446.497 us; speedup 1.0000x reference)
//
#include <hip/hip_runtime.h>
#include <hip/hip_bf16.h>

// Problem constants
#define D_MODEL 1024
#define SEQ     2048
#define BATCH   2
#define NH      8
#define HD      128   // D_MODEL / NH
#define MTOT    4096  // BATCH * SEQ

typedef __attribute__((ext_vector_type(4))) float f32x4;
typedef __attribute__((ext_vector_type(8))) short bf16x8;

// Workspace: fp32 R occupies ws[0..4M) floats; bf16 region starts at ws+4M.
// bf16 element offsets within the bf16 region:
#define BF_XDE 0u          // [m][k] 4M
#define BF_XEN 4194304u    // [m][k] 4M
#define BF_WQT 8388608u    // [n][k] 1M (Wk/Wv/Wo follow at +1M each)
#define BF_WOT 11534336u
#define BF_QB  12582912u   // [bh][l][c] 4M
#define BF_KB  16777216u
#define BF_VT  20971520u   // [bh][c][l] 4M
#define BF_AB  25165824u   // [m][n] 4M (attention out)
#define BF_MB  29360128u   // packed mask bits: 262144 uint64 = 2 MB

__device__ __forceinline__ float4 ldg4(const float* p) {
  return *reinterpret_cast<const float4*>(p);
}

__device__ __forceinline__ void load_lds16(const void* g, void* l) {
  __builtin_amdgcn_global_load_lds((const __attribute__((address_space(1))) void*)g,
                                   (__attribute__((address_space(3))) void*)l, 16, 0, 0);
}

// barrier that drains only LDS ops (keeps global prefetch loads in flight)
__device__ __forceinline__ void barrier_lgkm() {
  asm volatile("s_waitcnt lgkmcnt(0)" ::: "memory");
  __builtin_amdgcn_s_barrier();
}

// ---------------------------------------------------------------------------
// Pack int32 mask -> bitmask (bit j of word w = mask[w*64+j] != 0)
// ---------------------------------------------------------------------------
__global__ __launch_bounds__(256) void mask_pack_kernel(const int* __restrict__ mask,
                                                        unsigned long long* __restrict__ Mb) {
  const int lane = threadIdx.x & 63;
  const int gw = blockIdx.x * 4 + (threadIdx.x >> 6);
  const int nw = gridDim.x * 4;
  const int nwords = (BATCH * SEQ * SEQ) / 64;
  for (int w = gw; w < nwords; w += nw) {
    const int v = mask[(size_t)w * 64 + lane];
    const unsigned long long bits = __ballot(v != 0);
    if (lane == 0) Mb[w] = bits;
  }
}

// ---------------------------------------------------------------------------
// Cast activations fp32 -> bf16 row-major [m][k]. 1024x2 blocks, 16 elem/thr.
// ---------------------------------------------------------------------------
__global__ __launch_bounds__(256) void castx_kernel(const float* __restrict__ de,
                                                    const float* __restrict__ en,
                                                    __hip_bfloat16* __restrict__ Xde,
                                                    __hip_bfloat16* __restrict__ Xen) {
  const float* src = blockIdx.y ? en : de;
  __hip_bfloat16* dst = blockIdx.y ? Xen : Xde;
  const size_t base = (size_t)blockIdx.x * 4096 + (size_t)threadIdx.x * 16;
  float tmp[16];
#pragma unroll
  for (int i = 0; i < 4; ++i) {
    const float4 v = ldg4(src + base + i * 4);
    tmp[i * 4 + 0] = v.x; tmp[i * 4 + 1] = v.y; tmp[i * 4 + 2] = v.z; tmp[i * 4 + 3] = v.w;
  }
  __hip_bfloat16 ob[16];
#pragma unroll
  for (int i = 0; i < 16; ++i) ob[i] = __float2bfloat16(tmp[i]);
  *reinterpret_cast<uint4*>(dst + base)     = *reinterpret_cast<const uint4*>(ob);
  *reinterpret_cast<uint4*>(dst + base + 8) = *reinterpret_cast<const uint4*>(ob + 8);
}

// ---------------------------------------------------------------------------
// Cast + transpose weights: W[k][n] fp32 -> Wt[n][k] bf16. 64x64 tiles.
// ---------------------------------------------------------------------------
__global__ __launch_bounds__(256) void castw_kernel(const float* __restrict__ Wq,
                                                    const float* __restrict__ Wk,
                                                    const float* __restrict__ Wv,
                                                    const float* __restrict__ Wo,
                                                    __hip_bfloat16* __restrict__ WtBase) {
  __shared__ __hip_bfloat16 tile[64][68];
  const int z = blockIdx.z;
  const float* W = (z == 0) ? Wq : (z == 1) ? Wk : (z == 2) ? Wv : Wo;
  __hip_bfloat16* Wt = WtBase + (size_t)z * 1048576;
  const int n0 = blockIdx.x * 64, k0 = blockIdx.y * 64;
  const int t = threadIdx.x;
#pragma unroll
  for (int i = 0; i < 4; ++i) {
    const int kr = (t >> 4) + i * 16, cg = t & 15;
    const float4 v = ldg4(W + (size_t)(k0 + kr) * D_MODEL + n0 + cg * 4);
    __hip_bfloat16 tb[4] = {__float2bfloat16(v.x), __float2bfloat16(v.y),
                            __float2bfloat16(v.z), __float2bfloat16(v.w)};
    *reinterpret_cast<ushort4*>(&tile[kr][cg * 4]) = *reinterpret_cast<const ushort4*>(tb);
  }
  __syncthreads();
  const int nr = t >> 2, ks = (t & 3) * 16;
  __hip_bfloat16 ob[16];
#pragma unroll
  for (int j = 0; j < 16; ++j) ob[j] = tile[ks + j][nr];
  __hip_bfloat16* dst = Wt + (size_t)(n0 + nr) * D_MODEL + k0 + ks;
  *reinterpret_cast<uint4*>(dst)     = *reinterpret_cast<const uint4*>(ob);
  *reinterpret_cast<uint4*>(dst + 8) = *reinterpret_cast<const uint4*>(ob + 8);
}

// ---------------------------------------------------------------------------
// MFMA GEMM core (m97 structure): C 128x128 tile = A[m][k] * Bt[n][k]^T,
// K=1024, BK=64, 4 waves 2x2, global_load_lds width-16 staging.
// ---------------------------------------------------------------------------
__device__ __forceinline__ void mfma_core(const __hip_bfloat16* __restrict__ Ag,
                                          const __hip_bfloat16* __restrict__ Bg,
                                          int m0, int n0,
                                          __hip_bfloat16* Asm, __hip_bfloat16* Bsm,
                                          f32x4 acc[4][4]) {
  const int t = threadIdx.x, w = t >> 6, l = t & 63;
  const int lr = l & 15, lg = l >> 4;
  const int wr = w >> 1, wc = w & 1;
  const int lrow = l >> 3;
  const int lcol = (l & 7) * 8;

#pragma unroll
  for (int a = 0; a < 4; ++a)
#pragma unroll
    for (int b = 0; b < 4; ++b) acc[a][b] = (f32x4){0.f, 0.f, 0.f, 0.f};

  for (int ks = 0; ks < D_MODEL / 64; ++ks) {
    __syncthreads();
#pragma unroll
    for (int j = 0; j < 4; ++j) {
      const int chunk = w * 4 + j;
      const int row = chunk * 8 + lrow;
      load_lds16(Ag + (size_t)(m0 + row) * D_MODEL + ks * 64 + lcol, Asm + chunk * 512);
      load_lds16(Bg + (size_t)(n0 + row) * D_MODEL + ks * 64 + lcol, Bsm + chunk * 512);
    }
    __syncthreads();
#pragma unroll
    for (int kk = 0; kk < 2; ++kk) {
      bf16x8 af[4], bf[4];
#pragma unroll
      for (int fm = 0; fm < 4; ++fm)
        af[fm] = *reinterpret_cast<const bf16x8*>(Asm + (wr * 64 + fm * 16 + lr) * 64 + kk * 32 + lg * 8);
#pragma unroll
      for (int fn = 0; fn < 4; ++fn)
        bf[fn] = *reinterpret_cast<const bf16x8*>(Bsm + (wc * 64 + fn * 16 + lr) * 64 + kk * 32 + lg * 8);
#pragma unroll
      for (int fm = 0; fm < 4; ++fm)
#pragma unroll
        for (int fn = 0; fn < 4; ++fn)
          acc[fm][fn] = __builtin_amdgcn_mfma_f32_16x16x32_bf16(af[fm], bf[fn], acc[fm][fn], 0, 0, 0);
    }
  }
}

// ---------------------------------------------------------------------------
// QKV GEMM with LDS-staged coalesced epilogue.
// z=0 Q, z=1 K -> [bh][l][c]; z=2 V -> [bh][c][l]. Head split h=n%8, c=n/8.
// ---------------------------------------------------------------------------
__global__ __launch_bounds__(256, 2) void gemm_qkv_kernel(
    const __hip_bfloat16* __restrict__ Xde, const __hip_bfloat16* __restrict__ Xen,
    const __hip_bfloat16* __restrict__ WtQ,
    const float* __restrict__ bq, const float* __restrict__ bk, const float* __restrict__ bv,
    __hip_bfloat16* __restrict__ Qb, __hip_bfloat16* __restrict__ Kb,
    __hip_bfloat16* __restrict__ Vt) {
  __shared__ __hip_bfloat16 smem[16896];  // A(8192) + B(8192) staging; reused as 128x132 C-tile
  const int z = blockIdx.z;
  const __hip_bfloat16* Ag = (z == 0) ? Xde : Xen;
  const __hip_bfloat16* Bg = WtQ + (size_t)z * 1048576;
  const float* bias = (z == 0) ? bq : (z == 1) ? bk : bv;
  const int m0 = blockIdx.y * 128, n0 = blockIdx.x * 128;
  f32x4 acc[4][4];
  mfma_core(Ag, Bg, m0, n0, smem, smem + 8192, acc);

  const int t = threadIdx.x, w = t >> 6, l = t & 63;
  const int lr = l & 15, lg = l >> 4, wr = w >> 1, wc = w & 1;

  // stage C tile (bias added, bf16) into LDS for coalesced global writes
  __syncthreads();
  __hip_bfloat16 (*Ct)[132] = reinterpret_cast<__hip_bfloat16(*)[132]>(smem);
#pragma unroll
  for (int fn = 0; fn < 4; ++fn) {
    const int nl = wc * 64 + fn * 16 + lr;
    const float bve = bias[n0 + nl];
#pragma unroll
    for (int fm = 0; fm < 4; ++fm) {
      const int ml = wr * 64 + fm * 16 + lg * 4;
#pragma unroll
      for (int i = 0; i < 4; ++i)
        Ct[ml + i][nl] = __float2bfloat16(acc[fm][fn][i] + bve);
    }
  }
  __syncthreads();

  const int b = m0 >> 11, l0 = m0 & 2047, c0 = n0 >> 3;
  if (z != 2) {
    __hip_bfloat16* dst = (z == 0) ? Qb : Kb;
#pragma unroll
    for (int j = 0; j < 8; ++j) {
      const int cid = t + j * 256;                 // 8h x 128ll x 2half
      const int hh = cid >> 8, ll = (cid >> 1) & 127, half = cid & 1;
      __hip_bfloat16 ob[8];
#pragma unroll
      for (int cc = 0; cc < 8; ++cc)
        ob[cc] = Ct[ll][(half * 8 + cc) * 8 + hh];
      *reinterpret_cast<uint4*>(dst + ((size_t)(b * NH + hh) * SEQ + l0 + ll) * HD + c0 + half * 8) =
          *reinterpret_cast<const uint4*>(ob);
    }
  } else {
#pragma unroll
    for (int j = 0; j < 8; ++j) {
      const int cid = t + j * 256;                 // 128 n x 16 l-chunks
      const int nl = cid >> 4, chunk = cid & 15;
      const int n = n0 + nl;
      const int hh = n & 7, c = n >> 3;
      __hip_bfloat16 ob[8];
#pragma unroll
      for (int cc = 0; cc < 8; ++cc)
        ob[cc] = Ct[chunk * 8 + cc][nl];
      *reinterpret_cast<uint4*>(Vt + ((size_t)(b * NH + hh) * HD + c) * SEQ + l0 + chunk * 8) =
          *reinterpret_cast<const uint4*>(ob);
    }
  }
}

// ---------------------------------------------------------------------------
// Out projection: R = Ab@Wo + bo + de  (fp32 out for LN)
// ---------------------------------------------------------------------------
__global__ __launch_bounds__(256, 2) void gemm_out_kernel(
    const __hip_bfloat16* __restrict__ Ab, const __hip_bfloat16* __restrict__ Wot,
    const float* __restrict__ bo, const float* __restrict__ de,
    float* __restrict__ R) {
  __shared__ __hip_bfloat16 Asm[128 * 64];
  __shared__ __hip_bfloat16 Bsm[128 * 64];
  const int m0 = blockIdx.y * 128, n0 = blockIdx.x * 128;
  f32x4 acc[4][4];
  mfma_core(Ab, Wot, m0, n0, Asm, Bsm, acc);

  const int t = threadIdx.x, w = t >> 6, l = t & 63;
  const int lr = l & 15, lg = l >> 4, wr = w >> 1, wc = w & 1;
#pragma unroll
  for (int fn = 0; fn < 4; ++fn) {
    const int n = n0 + wc * 64 + fn * 16 + lr;
    const float bve = bo[n];
#pragma unroll
    for (int fm = 0; fm < 4; ++fm)
#pragma unroll
      for (int i = 0; i < 4; ++i) {
        const int m = m0 + wr * 64 + fm * 16 + lg * 4 + i;
        R[(size_t)m * D_MODEL + n] = acc[fm][fn][i] + bve + de[(size_t)m * D_MODEL + n];
      }
  }
}

// ---------------------------------------------------------------------------
// MFMA flash attention, bitmask mask + T14 reg-prefetch K/V + T5 setprio.
// Grid (32 qtiles, 16 bh), 256 thr = 4 waves, BQ=64 (16 rows/wave), BKV=64.
// ---------------------------------------------------------------------------
__global__ __launch_bounds__(256, 3) void attn_kernel(const __hip_bfloat16* __restrict__ Qb,
                                                      const __hip_bfloat16* __restrict__ Kb,
                                                      const __hip_bfloat16* __restrict__ Vtb,
                                                      const unsigned long long* __restrict__ Mb,
                                                      __hip_bfloat16* __restrict__ Ab) {
  __shared__ __hip_bfloat16 Ks[64][136];
  __shared__ __hip_bfloat16 Vt[128][72];
  __shared__ __hip_bfloat16 Ps[64][72];

  const int qb = blockIdx.x, bh = blockIdx.y;
  const int b = bh >> 3, h = bh & 7;
  const int t = threadIdx.x;
  const int w = t >> 6, l = t & 63;
  const int lr = l & 15, lg = l >> 4;
  const int q0 = qb * 64;

  const __hip_bfloat16* Qg = Qb + (size_t)bh * SEQ * HD;
  const __hip_bfloat16* Kg = Kb + (size_t)bh * SEQ * HD;
  const __hip_bfloat16* Vg = Vtb + (size_t)bh * HD * SEQ;

  // Q fragments hoisted to registers (4 x bf16x8 = 16 VGPR)
  bf16x8 qf[4];
#pragma unroll
  for (int kc = 0; kc < 4; ++kc)
    qf[kc] = *reinterpret_cast<const bf16x8*>(Qg + (size_t)(q0 + w * 16 + lr) * HD + kc * 32 + lg * 8);

  // K/V register prefetch (T14 issue-early / write-late)
  uint4 kreg[4], vreg[4];
  auto prefetch = [&](int kt) {
    const int k0 = kt * 64;
#pragma unroll
    for (int it = 0; it < 4; ++it) {
      const int idx = t + it * 256;
      kreg[it] = *reinterpret_cast<const uint4*>(Kg + (size_t)(k0 + (idx >> 4)) * HD + (idx & 15) * 8);
      vreg[it] = *reinterpret_cast<const uint4*>(Vg + (size_t)(idx >> 3) * SEQ + k0 + (idx & 7) * 8);
    }
  };
  prefetch(0);

  const unsigned long long* Mrow = Mb + ((size_t)b * SEQ + q0 + w * 16 + lg * 4) * 32;

  float m_run[4], l_run[4];
  f32x4 o[8];
#pragma unroll
  for (int i = 0; i < 4; ++i) { m_run[i] = -INFINITY; l_run[i] = 0.f; }
#pragma unroll
  for (int dt = 0; dt < 8; ++dt) o[dt] = (f32x4){0.f, 0.f, 0.f, 0.f};

  for (int kt = 0; kt < SEQ / 64; ++kt) {
    barrier_lgkm();   // previous tile's LDS reads complete (consumed by MFMA deps)
    // commit staged regs -> LDS
#pragma unroll
    for (int it = 0; it < 4; ++it) {
      const int idx = t + it * 256;
      *reinterpret_cast<uint4*>(&Ks[idx >> 4][(idx & 15) * 8]) = kreg[it];
      *reinterpret_cast<uint4*>(&Vt[idx >> 3][(idx & 7) * 8]) = vreg[it];
    }
    // mask words for this tile (issued BEFORE prefetch so their vmcnt wait
    // does not drain the K/V prefetch loads)
    unsigned long long mw[4];
#pragma unroll
    for (int i = 0; i < 4; ++i) mw[i] = Mrow[(size_t)i * 32 + kt];
    if (kt + 1 < SEQ / 64) prefetch(kt + 1);  // in flight across the barrier
    barrier_lgkm();   // LDS writes visible; global prefetch NOT drained

    // S = Q K^T : wave's 16 rows x 64 cols
    f32x4 s[4];
#pragma unroll
    for (int nt = 0; nt < 4; ++nt) s[nt] = (f32x4){0.f, 0.f, 0.f, 0.f};
    __builtin_amdgcn_s_setprio(1);
#pragma unroll
    for (int kc = 0; kc < 4; ++kc) {
#pragma unroll
      for (int nt = 0; nt < 4; ++nt) {
        const bf16x8 bfr = *reinterpret_cast<const bf16x8*>(&Ks[nt * 16 + lr][kc * 32 + lg * 8]);
        s[nt] = __builtin_amdgcn_mfma_f32_16x16x32_bf16(qf[kc], bfr, s[nt], 0, 0, 0);
      }
    }
    __builtin_amdgcn_s_setprio(0);

    // mask + scale + online softmax; rows handled by this lane: lg*4+i
    float p[4][4];
#pragma unroll
    for (int i = 0; i < 4; ++i) {
      const unsigned long long mwi = mw[i];
      float v0 = ((mwi >> (lr))      & 1ull) ? -1e10f : s[0][i] * 0.03125f;
      float v1 = ((mwi >> (16 + lr)) & 1ull) ? -1e10f : s[1][i] * 0.03125f;
      float v2 = ((mwi >> (32 + lr)) & 1ull) ? -1e10f : s[2][i] * 0.03125f;
      float v3 = ((mwi >> (48 + lr)) & 1ull) ? -1e10f : s[3][i] * 0.03125f;
      p[0][i] = v0; p[1][i] = v1; p[2][i] = v2; p[3][i] = v3;

      float rm = fmaxf(fmaxf(v0, v1), fmaxf(v2, v3));
      rm = fmaxf(rm, __shfl_xor(rm, 1, 64));
      rm = fmaxf(rm, __shfl_xor(rm, 2, 64));
      rm = fmaxf(rm, __shfl_xor(rm, 4, 64));
      rm = fmaxf(rm, __shfl_xor(rm, 8, 64));
      const float mn = fmaxf(m_run[i], rm);
      const float sf = __expf(m_run[i] - mn);
      m_run[i] = mn;
      float rs = 0.f;
#pragma unroll
      for (int nt = 0; nt < 4; ++nt) {
        const float pe = __expf(p[nt][i] - mn);
        p[nt][i] = pe;
        rs += pe;
      }
      rs += __shfl_xor(rs, 1, 64);
      rs += __shfl_xor(rs, 2, 64);
      rs += __shfl_xor(rs, 4, 64);
      rs += __shfl_xor(rs, 8, 64);
      l_run[i] = l_run[i] * sf + rs;
#pragma unroll
      for (int dt = 0; dt < 8; ++dt) o[dt][i] *= sf;
      // P -> LDS (bf16), wave-private rows: no barrier needed
#pragma unroll
      for (int nt = 0; nt < 4; ++nt)
        Ps[w * 16 + lg * 4 + i][nt * 16 + lr] = __float2bfloat16(p[nt][i]);
    }

    // O += P V
    __builtin_amdgcn_s_setprio(1);
#pragma unroll
    for (int ksb = 0; ksb < 2; ++ksb) {
      const bf16x8 pa = *reinterpret_cast<const bf16x8*>(&Ps[w * 16 + lr][ksb * 32 + lg * 8]);
#pragma unroll
      for (int dt = 0; dt < 8; ++dt) {
        const bf16x8 vb = *reinterpret_cast<const bf16x8*>(&Vt[dt * 16 + lr][ksb * 32 + lg * 8]);
        o[dt] = __builtin_amdgcn_mfma_f32_16x16x32_bf16(pa, vb, o[dt], 0, 0, 0);
      }
    }
    __builtin_amdgcn_s_setprio(0);
  }

  // epilogue: Ab[b][q][h*128 + d] bf16
  __hip_bfloat16* Abp = Ab + ((size_t)b * SEQ + q0 + w * 16 + lg * 4) * D_MODEL + h * HD + lr;
#pragma unroll
  for (int i = 0; i < 4; ++i) {
    const float inv = 1.f / l_run[i];
#pragma unroll
    for (int dt = 0; dt < 8; ++dt)
      Abp[(size_t)i * D_MODEL + dt * 16] = __float2bfloat16(o[dt][i] * inv);
  }
}

// ---------------------------------------------------------------------------
// LayerNorm, unbiased var (ddof=1), eps=1e-8. One block (256 thr) per row.
// ---------------------------------------------------------------------------
__global__ __launch_bounds__(256) void ln_kernel(const float* __restrict__ R,
                                                 const float* __restrict__ gptr,
                                                 const float* __restrict__ bptr,
                                                 float* __restrict__ out) {
  __shared__ float red[8];
  const int m = blockIdx.x, t = threadIdx.x;
  const int lane = t & 63, wid = t >> 6;
  const float4 x = ldg4(R + (size_t)m * D_MODEL + t * 4);
  float s = x.x + x.y + x.z + x.w;
#pragma unroll
  for (int off = 1; off < 64; off <<= 1) s += __shfl_xor(s, off, 64);
  if (lane == 0) red[wid] = s;
  __syncthreads();
  const float mu = (red[0] + red[1] + red[2] + red[3]) * (1.f / 1024.f);
  const float dx = x.x - mu, dy = x.y - mu, dz = x.z - mu, dw = x.w - mu;
  float sq = dx * dx + dy * dy + dz * dz + dw * dw;
#pragma unroll
  for (int off = 1; off < 64; off <<= 1) sq += __shfl_xor(sq, off, 64);
  if (lane == 0) red[4 + wid] = sq;
  __syncthreads();
  const float var = (red[4] + red[5] + red[6] + red[7]) * (1.f / 1023.f);
  const float inv = rsqrtf(var + 1e-8f);
  const float g = gptr[0], be = bptr[0];
  float4 ov;
  ov.x = g * dx * inv + be;
  ov.y = g * dy * inv + be;
  ov.z = g * dz * inv + be;
  ov.w = g * dw * inv + be;
  *reinterpret_cast<float4*>(&out[(size_t)m * D_MODEL + t * 4]) = ov;
}

// ---------------------------------------------------------------------------
extern "C" void kernel_launch(void* const* d_in, const int* in_sizes, int n_in,
                              void* d_out, int out_size, void* d_ws, size_t ws_size,
                              hipStream_t stream) {
  const float* en   = (const float*)d_in[0];
  const float* de   = (const float*)d_in[1];
  const int*   mask = (const int*)d_in[2];
  const float* Wq   = (const float*)d_in[3];
  const float* bq   = (const float*)d_in[4];
  const float* Wk   = (const float*)d_in[5];
  const float* bk   = (const float*)d_in[6];
  const float* Wv   = (const float*)d_in[7];
  const float* bv   = (const float*)d_in[8];
  const float* Wo   = (const float*)d_in[9];
  const float* bo   = (const float*)d_in[10];
  const float* gamma = (const float*)d_in[11];
  const float* beta  = (const float*)d_in[12];
  float* ws  = (float*)d_ws;
  float* out = (float*)d_out;

  float* R = ws;                                            // 4M floats
  __hip_bfloat16* bfb = (__hip_bfloat16*)(ws + 4194304);    // bf16 region
  __hip_bfloat16* Xde = bfb + BF_XDE;
  __hip_bfloat16* Xen = bfb + BF_XEN;
  __hip_bfloat16* Wqt = bfb + BF_WQT;   // Wkt/Wvt/Wot follow at +1M each
  __hip_bfloat16* Wot = bfb + BF_WOT;
  __hip_bfloat16* Qb  = bfb + BF_QB;
  __hip_bfloat16* Kb  = bfb + BF_KB;
  __hip_bfloat16* Vt  = bfb + BF_VT;
  __hip_bfloat16* Ab  = bfb + BF_AB;
  unsigned long long* Mb = (unsigned long long*)(bfb + BF_MB);

  castx_kernel<<<dim3(1024, 2), 256, 0, stream>>>(de, en, Xde, Xen);
  castw_kernel<<<dim3(16, 16, 4), 256, 0, stream>>>(Wq, Wk, Wv, Wo, Wqt);
  mask_pack_kernel<<<1024, 256, 0, stream>>>(mask, Mb);
  gemm_qkv_kernel<<<dim3(8, 32, 3), 256, 0, stream>>>(Xde, Xen, Wqt, bq, bk, bv, Qb, Kb, Vt);
  attn_kernel<<<dim3(32, 16), 256, 0, stream>>>(Qb, Kb, Vt, Mb, Ab);
  gemm_out_kernel<<<dim3(8, 32), 256, 0, stream>>>(Ab, Wot, bo, de, R);
  ln_kernel<<<MTOT, 256, 0, stream>>>(R, gamma, beta, out);
}